// Round 3
// baseline (184.190 us; speedup 1.0000x reference)
//
#include <hip/hip_runtime.h>

constexpr int   T   = 4096;
constexpr float VTH = 1.27f;
constexpr int   K   = 32;         // time chunks per row
constexpr int   L   = T / K;      // 128 steps per chunk
constexpr int   LG  = L / 4;      // 32 float4 groups per chunk
constexpr int   WG  = 160;        // warm-up groups = 640 steps (lock fail ~e^-7.3 = 0.068%/boundary)

// ---- h-mask LIF machine (bitwise-validated vs reference: absmax 0.0) ----
// h bit j == spike at (t-1-j). gate (carried) == spike in [t-5, t-1].
__device__ __forceinline__ bool sstep(float x, float decay, float& v, unsigned& h, bool& gate) {
    float t1 = __fmul_rn(decay, v);
    float vd = __fsub_rn(v, t1);           // unfused — matches reference rounding
    float xe = gate ? 0.0f : x;
    float vn = __fadd_rn(vd, xe);
    bool  s  = vn > VTH;
    v = s ? 0.0f : vn;
    bool g4 = (h & 15u) != 0u;
    h = (h << 1) | (s ? 1u : 0u);
    gate = s || g4;
    return s;
}

// vo, so for step t; dvo = dv[t-1] (zero iff spike in [t-6, t]).
__device__ __forceinline__ bool ostep(float x, float decay, float& v, unsigned& h, bool& gate,
                                      float& vo, float& so, float& dvo, float xprev) {
    float t1 = __fmul_rn(decay, v);
    float vd = __fsub_rn(v, t1);
    float xe = gate ? 0.0f : x;
    float vn = __fadd_rn(vd, xe);
    bool  s  = vn > VTH;
    vo = s ? VTH  : vn;
    so = s ? 1.0f : 0.0f;
    v  = s ? 0.0f : vn;
    bool z6 = s || ((h & 63u) != 0u);
    dvo = z6 ? 0.0f : xprev;
    bool g4 = (h & 15u) != 0u;
    h = (h << 1) | (s ? 1u : 0u);
    gate = s || g4;
    return s;
}

__device__ __forceinline__ void ogroup(float4 X, float decay, float& v, unsigned& h, bool& gate,
                                       float& xprev, float4& vo, float4& so,
                                       float& close, float& px, float& py, float& pz) {
    ostep(X.x, decay, v, h, gate, vo.x, so.x, close, xprev); xprev = X.x;
    ostep(X.y, decay, v, h, gate, vo.y, so.y, px,    xprev); xprev = X.y;
    ostep(X.z, decay, v, h, gate, vo.z, so.z, py,    xprev); xprev = X.z;
    ostep(X.w, decay, v, h, gate, vo.w, so.w, pz,    xprev); xprev = X.w;
}

// ---------------- input transpose: ode[B][T] -> xT[rowblk][group][lane] ----------------
// Consumer (lif_spec) lane l, group g reads xT[(blk*(T/4)+g)*64 + l]: 1 KB/instr, 8 full lines.
// Tile 64 rows x 8 groups (32 steps); XOR-swizzled LDS -> conflict-free both phases.
__global__ __launch_bounds__(256)
void xt_pass(const float* __restrict__ ode, float4* __restrict__ xT, int B) {
    __shared__ float4 tile[64][8];
    const int tid = threadIdx.x;
    const int ntt = T / 32;                       // time-tiles per row
    const int tt  = blockIdx.x % ntt;
    const int rb  = (blockIdx.x / ntt) * 64;      // row-block base
    const int g0  = tt * 8;
    const float4* __restrict__ x4g = (const float4*)ode;

    {   // read: 8 rows x 128 B contiguous per wave-instr (8 full lines)
        int r = tid >> 3, c = tid & 7;
        tile[r][c ^ (r & 7)]           = x4g[(size_t)(rb + r)      * (T / 4) + g0 + c];
        int r2 = r + 32;
        tile[r2][c ^ (r2 & 7)]         = x4g[(size_t)(rb + r2)     * (T / 4) + g0 + c];
    }
    __syncthreads();
    {   // write: 64 lanes x 16 B = 1 KB contiguous per instr
        int l = tid & 63, j = tid >> 6;           // j in 0..3
        size_t obase = ((size_t)(rb >> 6) * (T / 4) + g0) * 64;
        xT[obase + (size_t)j       * 64 + l] = tile[l][j       ^ (l & 7)];
        xT[obase + (size_t)(j + 4) * 64 + l] = tile[l][(j + 4) ^ (l & 7)];
    }
}

// ---------------- fused speculative chunk kernel ----------------
// Inputs via xT (coalesced). Outputs staged in XOR-swizzled LDS per 2-quad pair (32 steps),
// flushed as full-128B-per-row stores (8 full lines / instr). dv lags -> 2-slot ring of pairs.
__device__ __forceinline__ void flush_pair(int p, int tid, int rb, int k,
        float* __restrict__ vout, float* __restrict__ sout, float* __restrict__ dvout,
        const float4 (*tv)[8], const float4 (*ts)[8], const float4 (*td)[64][8]) {
    __syncthreads();
    const int cc = (tid & 7) ^ (tid >> 3);
#pragma unroll
    for (int jj = 0; jj < 8; ++jj) {
        int rr = jj * 8 + (tid >> 3);
        size_t off = (size_t)(rb + rr) * T + k * L + p * 32 + (tid & 7) * 4;
        *(float4*)(vout + off) = tv[rr][cc];
        *(float4*)(sout + off) = ts[rr][cc];
        if (p >= 1) *(float4*)(dvout + off - 32) = td[(p - 1) & 1][rr][cc];
    }
    __syncthreads();
}

__global__ __launch_bounds__(64, 1)
void lif_spec(const float4* __restrict__ xT, const float* __restrict__ decay_p,
              float* __restrict__ vout, float* __restrict__ sout, float* __restrict__ dvout,
              float2* __restrict__ Sst, float2* __restrict__ Est, int B) {
    __shared__ float4 tv[64][8];           // v: one 32-step pair slot
    __shared__ float4 ts[64][8];           // s
    __shared__ float4 td[2][64][8];        // dv: 2-slot pair ring (lags one pair)

    const int tid = threadIdx.x;
    const int gg  = blockIdx.x * 64;
    const int rb  = gg % B;                // row block base; wave = 64 consecutive rows
    const int k   = gg / B;                // wave-uniform chunk id
    const int b   = rb + tid;
    const float decay = decay_p[0];
    const int xs7 = tid & 7;

    const size_t xb = (size_t)(rb >> 6) * (T / 4) * 64 + tid;
#define XLD(g) xT[xb + (size_t)(g) * 64]

    const int g0f = k * LG;
    const int wg  = (k == 0) ? 0 : (k * LG < WG ? k * LG : WG);
    float v = 0.0f; unsigned h = 0u; bool gate = false;
    float xprev = 0.0f;

    // ---- warm-up (state only), 16-group-deep coalesced load pipeline.
    if (wg > 0) {
        const size_t xwb = xb + (size_t)(g0f - wg) * 64;
        const bool t0row = (g0f - wg == 0);
        float4 Q[16];
#pragma unroll
        for (int i = 0; i < 16; ++i) Q[i] = xT[xwb + (size_t)i * 64];
        for (int c = 0; c < wg; c += 16) {
#pragma unroll
            for (int i = 0; i < 16; ++i) {
                if (i == 0 && c == 0 && t0row) {   // t=0 spike does NOT arm the window
                    sstep(Q[0].x, decay, v, h, gate); h = 0u; gate = false;
                    sstep(Q[0].y, decay, v, h, gate);
                    sstep(Q[0].z, decay, v, h, gate);
                    sstep(Q[0].w, decay, v, h, gate);
                } else {
                    sstep(Q[i].x, decay, v, h, gate);
                    sstep(Q[i].y, decay, v, h, gate);
                    sstep(Q[i].z, decay, v, h, gate);
                    sstep(Q[i].w, decay, v, h, gate);
                }
                Q[i] = xT[xwb + (size_t)(c + i + 16) * 64];  // ≤ g0f+15: in-bounds
            }
        }
        Sst[k * B + b] = make_float2(v, __uint_as_float(h & 127u));
    }

    // ---- main: 4 pairs x 8 groups, A/B register pipeline (1 pair deep), LDS-staged outputs
    float4 A0 = XLD(g0f),     A1 = XLD(g0f + 1), A2 = XLD(g0f + 2), A3 = XLD(g0f + 3);
    float4 B0 = XLD(g0f + 4), B1 = XLD(g0f + 5), B2 = XLD(g0f + 6), B3 = XLD(g0f + 7);
    float4 Pd;                             // rolling dv group (xyz pending, w = close)

// group gidx (compile-time 0..31): compute, stage dv col gidx-1, stage v/s col gidx&7
#define OG(X, gidx) { float4 V_, S_; float cl_, p0_, p1_, p2_; \
        ogroup(X, decay, v, h, gate, xprev, V_, S_, cl_, p0_, p1_, p2_); \
        if ((gidx) > 0) { Pd.w = cl_; \
            td[(((gidx) - 1) >> 3) & 1][tid][(((gidx) - 1) & 7) ^ xs7] = Pd; } \
        Pd.x = p0_; Pd.y = p1_; Pd.z = p2_; \
        tv[tid][((gidx) & 7) ^ xs7] = V_; ts[tid][((gidx) & 7) ^ xs7] = S_; }

    {   // pair 0
        if (k == 0) {
            float4 V_, S_; float dvd;
            bool s0 = ostep(A0.x, decay, v, h, gate, V_.x, S_.x, dvd, xprev); xprev = A0.x;
            h = 0u; gate = false;          // t=0 spike doesn't arm the window
            bool s1 = ostep(A0.y, decay, v, h, gate, V_.y, S_.y, Pd.x, xprev); xprev = A0.y;
            ostep(A0.z, decay, v, h, gate, V_.z, S_.z, Pd.y, xprev); xprev = A0.z;
            ostep(A0.w, decay, v, h, gate, V_.w, S_.w, Pd.z, xprev); xprev = A0.w;
            if (s0 && s1) V_.z = VTH;      // counter==2 corner: spikes at t=0 and t=1
            tv[tid][xs7] = V_; ts[tid][xs7] = S_;
        } else {
            float4 V_, S_; float cl_;      // close = dv[t0-1]: owned by chunk k-1's lookahead
            ogroup(A0, decay, v, h, gate, xprev, V_, S_, cl_, Pd.x, Pd.y, Pd.z);
            tv[tid][xs7] = V_; ts[tid][xs7] = S_;
        }
        A0 = XLD(g0f + 8);
        OG(A1, 1) A1 = XLD(g0f + 9);
        OG(A2, 2) A2 = XLD(g0f + 10);
        OG(A3, 3) A3 = XLD(g0f + 11);
        OG(B0, 4) B0 = XLD(g0f + 12);
        OG(B1, 5) B1 = XLD(g0f + 13);
        OG(B2, 6) B2 = XLD(g0f + 14);
        OG(B3, 7) B3 = XLD(g0f + 15);
        flush_pair(0, tid, rb, k, vout, sout, dvout, tv, ts, td);
    }
    // pair 1
    OG(A0, 8)  A0 = XLD(g0f + 16); OG(A1, 9)  A1 = XLD(g0f + 17);
    OG(A2, 10) A2 = XLD(g0f + 18); OG(A3, 11) A3 = XLD(g0f + 19);
    OG(B0, 12) B0 = XLD(g0f + 20); OG(B1, 13) B1 = XLD(g0f + 21);
    OG(B2, 14) B2 = XLD(g0f + 22); OG(B3, 15) B3 = XLD(g0f + 23);
    flush_pair(1, tid, rb, k, vout, sout, dvout, tv, ts, td);
    // pair 2
    OG(A0, 16) A0 = XLD(g0f + 24); OG(A1, 17) A1 = XLD(g0f + 25);
    OG(A2, 18) A2 = XLD(g0f + 26); OG(A3, 19) A3 = XLD(g0f + 27);
    OG(B0, 20) B0 = XLD(g0f + 28); OG(B1, 21) B1 = XLD(g0f + 29);
    OG(B2, 22) B2 = XLD(g0f + 30); OG(B3, 23) B3 = XLD(g0f + 31);
    flush_pair(2, tid, rb, k, vout, sout, dvout, tv, ts, td);
    // pair 3 (no refill)
    OG(A0, 24) OG(A1, 25) OG(A2, 26) OG(A3, 27)
    OG(B0, 28) OG(B1, 29) OG(B2, 30) OG(B3, 31)
    flush_pair(3, tid, rb, k, vout, sout, dvout, tv, ts, td);
#undef OG

    Est[k * B + b] = make_float2(v, __uint_as_float(h & 127u));   // exit, pre-lookahead

    if (k < K - 1) {                       // lookahead closes dv[t0+L-1]
        float xla = XLD((k + 1) * LG).x;
        float vo_, so_;
        ostep(xla, decay, v, h, gate, vo_, so_, Pd.w, xprev);
    } else {
        Pd.w = ((h & 63u) != 0u) ? 0.0f : xprev;   // dv[T-1]
    }
    td[1][tid][7 ^ xs7] = Pd;              // col 31: pair 3 -> ring slot 1, local col 7
    __syncthreads();
    {   // flush dv pair 3 (ring slot 1)
        const int cc = (tid & 7) ^ (tid >> 3);
#pragma unroll
        for (int jj = 0; jj < 8; ++jj) {
            int rr = jj * 8 + (tid >> 3);
            size_t off = (size_t)(rb + rr) * T + k * L + 3 * 32 + (tid & 7) * 4;
            *(float4*)(dvout + off) = td[1][rr][cc];
        }
    }
#undef XLD
}

// ---------------- verify + rare chunk-granular repair (exact by induction) ----------------
__global__ __launch_bounds__(64, 1)
void lif_fix(const float* __restrict__ ode, const float* __restrict__ decay_p,
             float* __restrict__ vout, float* __restrict__ sout, float* __restrict__ dvout,
             const float2* __restrict__ Sst, const float2* __restrict__ Est, int B) {
    const int b = blockIdx.x * 64 + threadIdx.x;
    const float decay = decay_p[0];

    float2 E  = Est[b];                    // chunk 0 exit — exact
    float2 S1 = Sst[B + b];
    float2 E1 = Est[B + b];
    for (int k = 1; k < K; ++k) {
        float2 S = S1, Ek = E1;
        if (k + 1 < K) { S1 = Sst[(k + 1) * B + b]; E1 = Est[(k + 1) * B + b]; }
        bool match = (S.x == E.x) && (__float_as_uint(S.y) == __float_as_uint(E.y));
        if (match) { E = Ek; continue; }

        // rerun chunk k from exact entry E, rewriting its outputs (4-group-deep load pipeline)
        const size_t bt = (size_t)b * T;
        const float4* __restrict__ x4 = (const float4*)(ode + bt);
        float4* __restrict__ v4 = (float4*)(vout + bt);
        float4* __restrict__ s4 = (float4*)(sout + bt);
        float4* __restrict__ d4 = (float4*)(dvout + bt);
        const int g0f = k * LG;

        float v = E.x; unsigned h = __float_as_uint(E.y);
        bool gate = (h & 31u) != 0u;
        float xprev = 0.0f;
        float4 pend;

        float4 Q0 = x4[g0f], Q1 = x4[g0f + 1], Q2 = x4[g0f + 2], Q3 = x4[g0f + 3];
        {   // group 0: close (dv[t0-1]) owned by chunk k-1's (exact) lookahead
            float4 vo, so; float cl;
            ogroup(Q0, decay, v, h, gate, xprev, vo, so, cl, pend.x, pend.y, pend.z);
            v4[g0f] = vo; s4[g0f] = so;
            Q0 = x4[g0f + 4];
        }
#define FPROC(cc, Q) { float4 vo, so; float px, py, pz; \
            ogroup(Q, decay, v, h, gate, xprev, vo, so, pend.w, px, py, pz); \
            d4[g0f + (cc) - 1] = pend; \
            pend.x = px; pend.y = py; pend.z = pz; \
            v4[g0f + (cc)] = vo; s4[g0f + (cc)] = so; }
        FPROC(1, Q1) Q1 = x4[g0f + 5];
        FPROC(2, Q2) Q2 = x4[g0f + 6];
        FPROC(3, Q3) Q3 = x4[g0f + 7];
        for (int c0 = 4; c0 < LG; c0 += 4) {
            FPROC(c0,     Q0) Q0 = x4[g0f + (c0 + 4 < LG ? c0 + 4 : LG - 1)];
            FPROC(c0 + 1, Q1) Q1 = x4[g0f + (c0 + 5 < LG ? c0 + 5 : LG - 1)];
            FPROC(c0 + 2, Q2) Q2 = x4[g0f + (c0 + 6 < LG ? c0 + 6 : LG - 1)];
            FPROC(c0 + 3, Q3) Q3 = x4[g0f + (c0 + 7 < LG ? c0 + 7 : LG - 1)];
        }
#undef FPROC
        E = make_float2(v, __uint_as_float(h & 127u));   // corrected exit
        if (k < K - 1) {
            float xla = ode[bt + (size_t)(k + 1) * L];
            float vo_, so_;
            ostep(xla, decay, v, h, gate, vo_, so_, pend.w, xprev);
        } else {
            pend.w = ((h & 63u) != 0u) ? 0.0f : xprev;
        }
        d4[g0f + LG - 1] = pend;
    }
}

extern "C" void kernel_launch(void* const* d_in, const int* in_sizes, int n_in,
                              void* d_out, int out_size, void* d_ws, size_t ws_size,
                              hipStream_t stream) {
    const float* ode   = (const float*)d_in[0];
    const float* decay = (const float*)d_in[1];
    float* out = (float*)d_out;

    const int BT = in_sizes[0];            // B*T
    const int B  = BT / T;                 // 2048

    float* vout  = out;
    float* sout  = out + (size_t)BT;
    float* dvout = out + 2 * (size_t)BT;

    float2* Sst = (float2*)d_ws;           // [K][B]
    float2* Est = Sst + (size_t)K * B;     // [K][B]  (1 MB total)
    float4* xT  = (float4*)((char*)d_ws + 2 * (size_t)K * B * sizeof(float2));  // 16B-aligned, B*T*4 bytes

    xt_pass<<<dim3((T / 32) * (B / 64)), dim3(256), 0, stream>>>(ode, xT, B);
    lif_spec<<<dim3((B * K) / 64), dim3(64), 0, stream>>>(xT, decay, vout, sout, dvout,
                                                          Sst, Est, B);
    lif_fix<<<dim3(B / 64), dim3(64), 0, stream>>>(ode, decay, vout, sout, dvout,
                                                   Sst, Est, B);
}

// Round 4
// 171.429 us; speedup vs baseline: 1.0744x; 1.0744x over previous
//
#include <hip/hip_runtime.h>

constexpr int   T   = 4096;
constexpr float VTH = 1.27f;
constexpr int   K   = 32;         // time chunks per row
constexpr int   L   = T / K;      // 128 steps per chunk
constexpr int   LG  = L / 4;      // 32 float4 groups per chunk
constexpr int   WGG = 160;        // warm-up groups = 640 steps (lock fail ~0.068%/boundary)

// ---- h-mask LIF machine (bitwise-validated vs reference: absmax 0.0) ----
// h bit j == spike at (t-1-j). gate (carried) == spike in [t-5, t-1].
__device__ __forceinline__ bool sstep(float x, float decay, float& v, unsigned& h, bool& gate) {
    float t1 = __fmul_rn(decay, v);
    float vd = __fsub_rn(v, t1);           // unfused — matches reference rounding
    float xe = gate ? 0.0f : x;
    float vn = __fadd_rn(vd, xe);
    bool  s  = vn > VTH;
    v = s ? 0.0f : vn;
    bool g4 = (h & 15u) != 0u;
    h = (h << 1) | (s ? 1u : 0u);
    gate = s || g4;
    return s;
}

// vo, so for step t; dvo = dv[t-1] (zero iff spike in [t-6, t]).
__device__ __forceinline__ bool ostep(float x, float decay, float& v, unsigned& h, bool& gate,
                                      float& vo, float& so, float& dvo, float xprev) {
    float t1 = __fmul_rn(decay, v);
    float vd = __fsub_rn(v, t1);
    float xe = gate ? 0.0f : x;
    float vn = __fadd_rn(vd, xe);
    bool  s  = vn > VTH;
    vo = s ? VTH  : vn;
    so = s ? 1.0f : 0.0f;
    v  = s ? 0.0f : vn;
    bool z6 = s || ((h & 63u) != 0u);
    dvo = z6 ? 0.0f : xprev;
    bool g4 = (h & 15u) != 0u;
    h = (h << 1) | (s ? 1u : 0u);
    gate = s || g4;
    return s;
}

__device__ __forceinline__ void ogroup(float4 X, float decay, float& v, unsigned& h, bool& gate,
                                       float& xprev, float4& vo, float4& so,
                                       float& close, float& px, float& py, float& pz) {
    ostep(X.x, decay, v, h, gate, vo.x, so.x, close, xprev); xprev = X.x;
    ostep(X.y, decay, v, h, gate, vo.y, so.y, px,    xprev); xprev = X.y;
    ostep(X.z, decay, v, h, gate, vo.z, so.z, py,    xprev); xprev = X.z;
    ostep(X.w, decay, v, h, gate, vo.w, so.w, pz,    xprev); xprev = X.w;
}

// explicit waits (NO __syncthreads in the streamed loop: its vmcnt(0) would drain the DMA
// pipeline). sched_barrier(0) after each asm wait per rule #18.
#define WVM(N) do { asm volatile("s_waitcnt vmcnt(" #N ")" ::: "memory"); \
                    __builtin_amdgcn_sched_barrier(0); } while (0)
#define WLG()  do { asm volatile("s_waitcnt lgkmcnt(0)" ::: "memory"); \
                    __builtin_amdgcn_sched_barrier(0); } while (0)

using GU32 = const __attribute__((address_space(1))) unsigned int;
using LU32 = __attribute__((address_space(3))) unsigned int;

// DMA one 64-row x 8-group tile global->LDS. Instr j: 8 rows x 128 B contiguous; LDS dest
// j*1024 + lane*16 == linear [64][8] float4 (row r = j*8+(lane>>3), col lane&7). The
// transpose layout matches global_load_lds's lane-linear dest exactly — no ds_writes.
__device__ __forceinline__ void stage8(const float* src0, float4* lbuf) {
    LU32* lp = (LU32*)lbuf;
#pragma unroll
    for (int j = 0; j < 8; ++j)
        __builtin_amdgcn_global_load_lds((GU32*)(src0 + (size_t)j * 8 * T),
                                         lp + j * 256, 16, 0, 0);
}

// end of pair p: flush v/s (pair p) and dv (pair p-1, complete since pair p's first close)
__device__ __forceinline__ void flush_pair(int p, int tid, int rb, int k,
        float* __restrict__ vout, float* __restrict__ sout, float* __restrict__ dvout,
        const float4 (*tv)[8], const float4 (*ts)[8], const float4 (*td)[64][8]) {
    WLG();                                 // all OG ds_writes landed (single-wave block)
    const int cc = (tid & 7) ^ (tid >> 3);
#pragma unroll
    for (int jj = 0; jj < 8; ++jj) {
        int rr = jj * 8 + (tid >> 3);
        size_t off = (size_t)(rb + rr) * T + k * L + p * 32 + (tid & 7) * 4;
        *(float4*)(vout + off) = tv[rr][cc];
        *(float4*)(sout + off) = ts[rr][cc];
        if (p >= 1) *(float4*)(dvout + off - 32) = td[(p - 1) & 1][rr][cc];
    }
    WLG();                                 // transposed reads done before next pair's writes
}

// ---------------- fused speculative chunk kernel (DMA-streamed input transpose) ----------------
__global__ __launch_bounds__(64, 1)
void lif_spec(const float* __restrict__ ode, const float* __restrict__ decay_p,
              float* __restrict__ vout, float* __restrict__ sout, float* __restrict__ dvout,
              float2* __restrict__ Sst, float2* __restrict__ Est, int B) {
    __shared__ float4 xin[64 * 8];         // input tile (single buffer, reg-consume-then-restage)
    __shared__ float4 tv[64][8];           // v: one 32-step pair slot
    __shared__ float4 ts[64][8];           // s
    __shared__ float4 td[2][64][8];        // dv: 2-slot pair ring (lags one pair)
                                           // total 40 KB -> 4 blocks/CU, all 1024 waves resident

    const int tid = threadIdx.x;
    const int gg  = blockIdx.x * 64;
    const int rb  = gg % B;                // row block base; wave = 64 consecutive rows
    const int k   = gg / B;                // wave-uniform chunk id
    const int b   = rb + tid;
    const float decay = decay_p[0];
    const int xs7 = tid & 7;

    const int g0f = k * LG;                                    // chunk start (groups)
    const int wgg = (k == 0) ? 0 : (g0f < WGG ? g0f : WGG);    // warm-up groups
    const int nw  = wgg >> 3;                                  // warm-up tiles (always even)
    const int gstart = g0f - wgg;                              // stream start (groups)

    float v = 0.0f; unsigned h = 0u; bool gate = false;
    float xprev = 0.0f;

    float xla = (k < K - 1) ? ode[(size_t)b * T + (size_t)(k + 1) * L] : 0.0f;

#define STAGE(t) stage8(ode + ((size_t)(rb + (tid >> 3)) * T \
                               + (size_t)(gstart + 8 * (t)) * 4 + (tid & 7) * 4), xin)
#define RD8 const float4* xr = xin + (size_t)tid * 8; \
            float4 G0 = xr[0], G1 = xr[1], G2 = xr[2], G3 = xr[3], \
                   G4 = xr[4], G5 = xr[5], G6 = xr[6], G7 = xr[7];
#define WG4(G) { sstep(G.x, decay, v, h, gate); sstep(G.y, decay, v, h, gate); \
                 sstep(G.z, decay, v, h, gate); sstep(G.w, decay, v, h, gate); }

    STAGE(0);                              // tile 0 in flight

    // ---- warm-up (state only). Chunks 1..5 cover the full prefix -> exact.
    if (nw > 0) {
        const bool t0row = (gstart == 0);
        for (int t = 0; t < nw; ++t) {
            WVM(0);                        // tile t resident (only loads outstanding)
            RD8
            WLG();                         // tile in regs -> safe to overwrite buffer
            STAGE(t + 1);                  // t+1 <= nw: last warm-up iter stages main tile 0
            if (t == 0 && t0row) {         // t=0 spike does NOT arm the window
                sstep(G0.x, decay, v, h, gate); h = 0u; gate = false;
                sstep(G0.y, decay, v, h, gate);
                sstep(G0.z, decay, v, h, gate);
                sstep(G0.w, decay, v, h, gate);
            } else { WG4(G0) }
            WG4(G1) WG4(G2) WG4(G3) WG4(G4) WG4(G5) WG4(G6) WG4(G7)
        }
    }

    // ---- main: 4 pairs x 8 groups. Counted vmcnt: newer-than-target ops only
    // (p1: F0=16; p2: F1=24; p3: F2=24). Extra compiler VMEM only strengthens the wait.
    float4 Pd;                             // rolling dv group (xyz pending, w = close)

#define OG(X, gidx) { float4 V_, S_; float cl_, p0_, p1_, p2_; \
        ogroup(X, decay, v, h, gate, xprev, V_, S_, cl_, p0_, p1_, p2_); \
        if ((gidx) > 0) { Pd.w = cl_; \
            td[(((gidx) - 1) >> 3) & 1][tid][(((gidx) - 1) & 7) ^ xs7] = Pd; } \
        Pd.x = p0_; Pd.y = p1_; Pd.z = p2_; \
        tv[tid][((gidx) & 7) ^ xs7] = V_; ts[tid][((gidx) & 7) ^ xs7] = S_; }

    {   // pair 0 (tile nw)
        WVM(0);
        RD8
        WLG();
        STAGE(nw + 1);
        if (nw > 0) Sst[k * B + b] = make_float2(v, __uint_as_float(h & 127u));
        if (k == 0) {
            float4 V_, S_; float dvd;
            bool s0 = ostep(G0.x, decay, v, h, gate, V_.x, S_.x, dvd, xprev); xprev = G0.x;
            h = 0u; gate = false;          // t=0 spike doesn't arm the window
            bool s1 = ostep(G0.y, decay, v, h, gate, V_.y, S_.y, Pd.x, xprev); xprev = G0.y;
            ostep(G0.z, decay, v, h, gate, V_.z, S_.z, Pd.y, xprev); xprev = G0.z;
            ostep(G0.w, decay, v, h, gate, V_.w, S_.w, Pd.z, xprev); xprev = G0.w;
            if (s0 && s1) V_.z = VTH;      // counter==2 corner: spikes at t=0 and t=1
            tv[tid][xs7] = V_; ts[tid][xs7] = S_;
        } else {
            float4 V_, S_; float cl_;      // close = dv[t0-1]: owned by chunk k-1's lookahead
            ogroup(G0, decay, v, h, gate, xprev, V_, S_, cl_, Pd.x, Pd.y, Pd.z);
            tv[tid][xs7] = V_; ts[tid][xs7] = S_;
        }
        OG(G1, 1) OG(G2, 2) OG(G3, 3) OG(G4, 4) OG(G5, 5) OG(G6, 6) OG(G7, 7)
        flush_pair(0, tid, rb, k, vout, sout, dvout, tv, ts, td);
    }
    {   // pair 1 (tile nw+1)
        WVM(16);
        RD8
        WLG();
        STAGE(nw + 2);
        OG(G0, 8)  OG(G1, 9)  OG(G2, 10) OG(G3, 11)
        OG(G4, 12) OG(G5, 13) OG(G6, 14) OG(G7, 15)
        flush_pair(1, tid, rb, k, vout, sout, dvout, tv, ts, td);
    }
    {   // pair 2 (tile nw+2)
        WVM(24);
        RD8
        WLG();
        STAGE(nw + 3);
        OG(G0, 16) OG(G1, 17) OG(G2, 18) OG(G3, 19)
        OG(G4, 20) OG(G5, 21) OG(G6, 22) OG(G7, 23)
        flush_pair(2, tid, rb, k, vout, sout, dvout, tv, ts, td);
    }
    {   // pair 3 (tile nw+3, no restage)
        WVM(24);
        RD8
        OG(G0, 24) OG(G1, 25) OG(G2, 26) OG(G3, 27)
        OG(G4, 28) OG(G5, 29) OG(G6, 30) OG(G7, 31)
        flush_pair(3, tid, rb, k, vout, sout, dvout, tv, ts, td);
    }
#undef OG
#undef RD8
#undef WG4
#undef STAGE

    Est[k * B + b] = make_float2(v, __uint_as_float(h & 127u));   // exit, pre-lookahead

    if (k < K - 1) {                       // lookahead closes dv[t0+L-1]
        float vo_, so_;
        ostep(xla, decay, v, h, gate, vo_, so_, Pd.w, xprev);
    } else {
        Pd.w = ((h & 63u) != 0u) ? 0.0f : xprev;   // dv[T-1]
    }
    td[1][tid][7 ^ xs7] = Pd;              // col 31: pair 3 -> ring slot 1, local col 7
    WLG();
    {   // flush dv pair 3 (ring slot 1)
        const int cc = (tid & 7) ^ (tid >> 3);
#pragma unroll
        for (int jj = 0; jj < 8; ++jj) {
            int rr = jj * 8 + (tid >> 3);
            size_t off = (size_t)(rb + rr) * T + k * L + 3 * 32 + (tid & 7) * 4;
            *(float4*)(dvout + off) = td[1][rr][cc];
        }
    }
}

// ---------------- verify + rare chunk-granular repair (exact by induction) ----------------
__global__ __launch_bounds__(64, 1)
void lif_fix(const float* __restrict__ ode, const float* __restrict__ decay_p,
             float* __restrict__ vout, float* __restrict__ sout, float* __restrict__ dvout,
             const float2* __restrict__ Sst, const float2* __restrict__ Est, int B) {
    const int b = blockIdx.x * 64 + threadIdx.x;
    const float decay = decay_p[0];

    float2 E  = Est[b];                    // chunk 0 exit — exact
    float2 S1 = Sst[B + b];
    float2 E1 = Est[B + b];
    for (int k = 1; k < K; ++k) {
        float2 S = S1, Ek = E1;
        if (k + 1 < K) { S1 = Sst[(k + 1) * B + b]; E1 = Est[(k + 1) * B + b]; }
        bool match = (S.x == E.x) && (__float_as_uint(S.y) == __float_as_uint(E.y));
        if (match) { E = Ek; continue; }

        // rerun chunk k from exact entry E, rewriting its outputs (4-group-deep load pipeline)
        const size_t bt = (size_t)b * T;
        const float4* __restrict__ x4 = (const float4*)(ode + bt);
        float4* __restrict__ v4 = (float4*)(vout + bt);
        float4* __restrict__ s4 = (float4*)(sout + bt);
        float4* __restrict__ d4 = (float4*)(dvout + bt);
        const int g0f = k * LG;

        float v = E.x; unsigned h = __float_as_uint(E.y);
        bool gate = (h & 31u) != 0u;
        float xprev = 0.0f;
        float4 pend;

        float4 Q0 = x4[g0f], Q1 = x4[g0f + 1], Q2 = x4[g0f + 2], Q3 = x4[g0f + 3];
        {   // group 0: close (dv[t0-1]) owned by chunk k-1's (exact) lookahead
            float4 vo, so; float cl;
            ogroup(Q0, decay, v, h, gate, xprev, vo, so, cl, pend.x, pend.y, pend.z);
            v4[g0f] = vo; s4[g0f] = so;
            Q0 = x4[g0f + 4];
        }
#define FPROC(cc, Q) { float4 vo, so; float px, py, pz; \
            ogroup(Q, decay, v, h, gate, xprev, vo, so, pend.w, px, py, pz); \
            d4[g0f + (cc) - 1] = pend; \
            pend.x = px; pend.y = py; pend.z = pz; \
            v4[g0f + (cc)] = vo; s4[g0f + (cc)] = so; }
        FPROC(1, Q1) Q1 = x4[g0f + 5];
        FPROC(2, Q2) Q2 = x4[g0f + 6];
        FPROC(3, Q3) Q3 = x4[g0f + 7];
        for (int c0 = 4; c0 < LG; c0 += 4) {
            FPROC(c0,     Q0) Q0 = x4[g0f + (c0 + 4 < LG ? c0 + 4 : LG - 1)];
            FPROC(c0 + 1, Q1) Q1 = x4[g0f + (c0 + 5 < LG ? c0 + 5 : LG - 1)];
            FPROC(c0 + 2, Q2) Q2 = x4[g0f + (c0 + 6 < LG ? c0 + 6 : LG - 1)];
            FPROC(c0 + 3, Q3) Q3 = x4[g0f + (c0 + 7 < LG ? c0 + 7 : LG - 1)];
        }
#undef FPROC
        E = make_float2(v, __uint_as_float(h & 127u));   // corrected exit
        if (k < K - 1) {
            float xla = ode[bt + (size_t)(k + 1) * L];
            float vo_, so_;
            ostep(xla, decay, v, h, gate, vo_, so_, pend.w, xprev);
        } else {
            pend.w = ((h & 63u) != 0u) ? 0.0f : xprev;
        }
        d4[g0f + LG - 1] = pend;
    }
}

extern "C" void kernel_launch(void* const* d_in, const int* in_sizes, int n_in,
                              void* d_out, int out_size, void* d_ws, size_t ws_size,
                              hipStream_t stream) {
    const float* ode   = (const float*)d_in[0];
    const float* decay = (const float*)d_in[1];
    float* out = (float*)d_out;

    const int BT = in_sizes[0];            // B*T
    const int B  = BT / T;                 // 2048

    float* vout  = out;
    float* sout  = out + (size_t)BT;
    float* dvout = out + 2 * (size_t)BT;

    float2* Sst = (float2*)d_ws;           // [K][B]
    float2* Est = Sst + (size_t)K * B;     // [K][B]  (1 MB total)

    lif_spec<<<dim3((B * K) / 64), dim3(64), 0, stream>>>(ode, decay, vout, sout, dvout,
                                                          Sst, Est, B);
    lif_fix<<<dim3(B / 64), dim3(64), 0, stream>>>(ode, decay, vout, sout, dvout,
                                                   Sst, Est, B);
}